// Round 10
// baseline (9092.463 us; speedup 1.0000x reference)
//
#include <hip/hip_runtime.h>

// RNN-VAE on MI355X. R10: pair TWO independent batch-groups per WG to hide
// the MALL exchange latency. 32 WGs = 4 N-split x 8 pairs; WG handles
// groups gA=2p, gB=2p+1 with SHARED weight pins (U fully reg-pinned, R8).
// Per step: compute A -> store A -> compute B -> store B -> [out-projA |
// poll A] -> [out-projB | poll B]; each group's ~2-RT exchange hides under
// the other group's work. Exchange protocol = R8 (proven): tagged
// self-validating 8B words, agent scope, waves 1-3 poll 2 slices each.

typedef __bf16 bf16x8 __attribute__((ext_vector_type(8)));
typedef float f32x4 __attribute__((ext_vector_type(4)));
typedef unsigned int uint4v __attribute__((ext_vector_type(4)));
typedef unsigned long long ull;

#define DI __device__ __forceinline__

DI unsigned short f2bf(float f) {            // fp32 -> bf16 RNE
  unsigned int u = __float_as_uint(f);
  u += 0x7fffu + ((u >> 16) & 1u);
  return (unsigned short)(u >> 16);
}
DI float sigf(float v) { return 1.0f / (1.0f + __expf(-v)); }

union FragU { bf16x8 v; unsigned short us[8]; };
union H8 { bf16x8 v; ull u[2]; uint4v q; };

DI f32x4 mfma16(bf16x8 a, bf16x8 b, f32x4 c) {
  return __builtin_amdgcn_mfma_f32_16x16x32_bf16(a, b, c, 0, 0, 0);
}
DI ull ald(const ull* p) {
  return __hip_atomic_load(p, __ATOMIC_RELAXED, __HIP_MEMORY_SCOPE_AGENT);
}

// ---- weight fragment packing (unchanged) ----
__global__ void pack_frags(const float* __restrict__ src,
                           unsigned short* __restrict__ dst, int K, int N) {
  int KT = K >> 5, NT = N >> 4;
  int total = KT * NT * 64;
  for (int idx = blockIdx.x * blockDim.x + threadIdx.x; idx < total;
       idx += gridDim.x * blockDim.x) {
    int lane = idx & 63;
    int fi = idx >> 6;
    int nt = fi % NT;
    int kt = fi / NT;
    int r0 = kt * 32 + (lane >> 4) * 8;
    int col = nt * 16 + (lane & 15);
    unsigned int w[4];
#pragma unroll
    for (int p = 0; p < 4; ++p) {
      unsigned int lo = f2bf(src[(size_t)(r0 + 2 * p) * N + col]);
      unsigned int hi = f2bf(src[(size_t)(r0 + 2 * p + 1) * N + col]);
      w[p] = lo | (hi << 16);
    }
    *(uint4v*)(dst + (size_t)idx * 8) = (uint4v){w[0], w[1], w[2], w[3]};
  }
}

// ---- per-(b,t) nonzero mask (unchanged) ----
__global__ void mask_flags(const float* __restrict__ x,
                           unsigned int* __restrict__ fmask) {
  const int t = blockIdx.x;
  const int b = threadIdx.x;
  const float* p = x + ((size_t)b * 1024 + t) * 128;
  bool nz = false;
#pragma unroll 8
  for (int k = 0; k < 32; ++k) {
    float4 v = *(const float4*)(p + k * 4);
    nz = nz || v.x != 0.f || v.y != 0.f || v.z != 0.f || v.w != 0.f;
  }
  unsigned long long bal = __ballot((int)nz);
  if ((threadIdx.x & 15) == 0)
    fmask[(size_t)(b >> 4) * 1024 + t] =
        (unsigned int)((bal >> (threadIdx.x & 48)) & 0xFFFFull);
}

// store own 2 kt-slices of HSTG as tagged 3-ull words (tid<128)
#define STORE_OWN(HSTG, HX, G, PAR, TAG) do {                               \
    if (tid < 128) {                                                        \
      const int kth = tid >> 6, word = tid & 63;                            \
      H8 hh; hh.q = *(const uint4v*)&(HSTG)[2 * s + kth][word][0];          \
      const ull tg = (ull)(TAG);                                            \
      ull Aw = (hh.u[0] & 0xFFFFFFFFFFFFULL) | (tg << 48);                  \
      ull Bw = ((hh.u[0] >> 48) | ((hh.u[1] & 0xFFFFFFFFULL) << 16)) |      \
               (tg << 48);                                                  \
      ull Cw = (hh.u[1] >> 32) | (tg << 48);                                \
      ull* p_ = (HX) + (size_t)((G) * 2 + (PAR)) * 1536 +                   \
                ((2 * s + kth) * 64 + word) * 3;                            \
      __hip_atomic_store(p_ + 0, Aw, __ATOMIC_RELAXED, __HIP_MEMORY_SCOPE_AGENT); \
      __hip_atomic_store(p_ + 1, Bw, __ATOMIC_RELAXED, __HIP_MEMORY_SCOPE_AGENT); \
      __hip_atomic_store(p_ + 2, Cw, __ATOMIC_RELAXED, __HIP_MEMORY_SCOPE_AGENT); \
    } } while (0)

// waves 1..3: poll partner WG's 2 kt-slices, write into HSTG
#define POLL_REMOTE(HSTG, HX, G, PAR, TAG) do {                             \
    if (w >= 1) {                                                           \
      const int s2_ = (w - 1) + ((w - 1) >= s ? 1 : 0);                     \
      const int rk0 = 2 * s2_, rk1 = rk0 + 1;                               \
      const ull* hb_ = (HX) + (size_t)((G) * 2 + (PAR)) * 1536;             \
      const ull* q0 = hb_ + (rk0 * 64 + lane) * 3;                          \
      const ull* q1 = hb_ + (rk1 * 64 + lane) * 3;                          \
      const ull tg = (ull)(TAG);                                            \
      ull A0, A1, A2, B0, B1, B2;                                           \
      unsigned it_ = 0;                                                     \
      for (;;) {                                                            \
        A0 = ald(q0); A1 = ald(q0 + 1); A2 = ald(q0 + 2);                   \
        B0 = ald(q1); B1 = ald(q1 + 1); B2 = ald(q1 + 2);                   \
        bool ok_ = ((A0 >> 48) == tg) && ((A1 >> 48) == tg) &&              \
                   ((A2 >> 48) == tg) && ((B0 >> 48) == tg) &&              \
                   ((B1 >> 48) == tg) && ((B2 >> 48) == tg);                \
        if (ok_ || ++it_ > (1u << 14)) break;                               \
      }                                                                     \
      H8 h0_, h1_;                                                          \
      h0_.u[0] = (A0 & 0xFFFFFFFFFFFFULL) | (A1 << 48);                     \
      h0_.u[1] = ((A1 >> 16) & 0xFFFFFFFFULL) | ((A2 & 0xFFFFFFFFULL) << 32); \
      h1_.u[0] = (B0 & 0xFFFFFFFFFFFFULL) | (B1 << 48);                     \
      h1_.u[1] = ((B1 >> 16) & 0xFFFFFFFFULL) | ((B2 & 0xFFFFFFFFULL) << 32); \
      *(uint4v*)&(HSTG)[rk0][lane][0] = h0_.q;                              \
      *(uint4v*)&(HSTG)[rk1][lane][0] = h1_.q;                              \
    } } while (0)

// =========================== encoder ======================================
__global__ __launch_bounds__(256) __attribute__((amdgpu_waves_per_eu(1, 1)))
void enc_rnn(const float* __restrict__ x,
             const unsigned short* __restrict__ Wef,
             const unsigned short* __restrict__ Uef,
             const float* __restrict__ benc,
             const unsigned int* __restrict__ fmask,
             ull* __restrict__ hxE,
             unsigned short* __restrict__ hfin) {
  __shared__ __align__(16) unsigned short hstA[8][64][8];   // 8KB
  __shared__ __align__(16) unsigned short hstB[8][64][8];   // 8KB

  const int tid = threadIdx.x;
  const int w = tid >> 6, lane = tid & 63;
  const int l15 = lane & 15, lkg = lane >> 4;
  const int bid = blockIdx.x;
  const int s = bid >> 3, p = bid & 7;
  const int gA = 2 * p, gB = 2 * p + 1;
  int ntf[4];
#pragma unroll
  for (int G = 0; G < 4; ++G) ntf[G] = G * 16 + s * 4 + w;

  const bf16x8* Wl = (const bf16x8*)Wef + lane;
  const bf16x8* Ul = (const bf16x8*)Uef + lane;

  bf16x8 upin[8][4];                         // U slice, shared by A and B
#pragma unroll
  for (int kt = 0; kt < 8; ++kt)
#pragma unroll
    for (int G = 0; G < 4; ++G) upin[kt][G] = Ul[(kt * 64 + ntf[G]) * 64];

  bf16x8 wpin[4][4];                         // W kt0..3, shared
#pragma unroll
  for (int G = 0; G < 4; ++G)
#pragma unroll
    for (int kt = 0; kt < 4; ++kt) wpin[G][kt] = Wl[(kt * 64 + ntf[G]) * 64];

  float bfr[4];
#pragma unroll
  for (int G = 0; G < 4; ++G) bfr[G] = benc[ntf[G] * 16 + l15];

  float cA[4], cB[4];
  unsigned short hgA[4], hgB[4];
  bf16x8 hfA[8], hfB[8];
#pragma unroll
  for (int q = 0; q < 4; ++q) { cA[q] = 0.f; cB[q] = 0.f; hgA[q] = 0; hgB[q] = 0; }
  H8 z_; z_.u[0] = 0; z_.u[1] = 0;
#pragma unroll
  for (int kt = 0; kt < 8; ++kt) { hfA[kt] = z_.v; hfB[kt] = z_.v; }

  const float* xbA = x + (size_t)(gA * 16 + l15) * 1024 * 128 + lkg * 8;
  const float* xbB = x + (size_t)(gB * 16 + l15) * 1024 * 128 + lkg * 8;
  const unsigned int* fpA = fmask + (size_t)gA * 1024;
  const unsigned int* fpB = fmask + (size_t)gB * 1024;
  const int kt_own = 2 * s + (w >> 1);
  const int lbase = (w & 1) * 32 + (l15 >> 3) * 16 + lkg * 4;
  const int jst = l15 & 7;
  int aA = 0, aB = 0;
  bool xvA = false, xvB = false;
  float4 xaA[4][2], xaB[4][2];

  __syncthreads();

  for (int t = 0; t < 1024; ++t) {
    const unsigned int flA = fpA[t], flB = fpB[t];

    if (flA) {                               // ---- A compute + store ----
      if (!xvA) {
        const float* xp = xbA + (size_t)t * 128;
#pragma unroll
        for (int kt = 0; kt < 4; ++kt) {
          xaA[kt][0] = *(const float4*)(xp + kt * 32);
          xaA[kt][1] = *(const float4*)(xp + kt * 32 + 4);
        }
      }
      f32x4 acc[4];
#pragma unroll
      for (int G = 0; G < 4; ++G) acc[G] = (f32x4){bfr[G], bfr[G], bfr[G], bfr[G]};
      FragU xf[4];
#pragma unroll
      for (int kt = 0; kt < 4; ++kt) {
        xf[kt].us[0] = f2bf(xaA[kt][0].x); xf[kt].us[1] = f2bf(xaA[kt][0].y);
        xf[kt].us[2] = f2bf(xaA[kt][0].z); xf[kt].us[3] = f2bf(xaA[kt][0].w);
        xf[kt].us[4] = f2bf(xaA[kt][1].x); xf[kt].us[5] = f2bf(xaA[kt][1].y);
        xf[kt].us[6] = f2bf(xaA[kt][1].z); xf[kt].us[7] = f2bf(xaA[kt][1].w);
      }
#pragma unroll
      for (int kt = 0; kt < 4; ++kt)
#pragma unroll
        for (int G = 0; G < 4; ++G) acc[G] = mfma16(xf[kt].v, wpin[G][kt], acc[G]);
#pragma unroll
      for (int kt = 0; kt < 8; ++kt)
#pragma unroll
        for (int G = 0; G < 4; ++G) acc[G] = mfma16(hfA[kt], upin[kt][G], acc[G]);

      unsigned short hv[4];
#pragma unroll
      for (int q = 0; q < 4; ++q) {
        float iv = sigf(acc[0][q]);
        float fv = sigf(acc[1][q]);
        float gv = fmaxf(acc[2][q], 0.f);
        float ov = sigf(acc[3][q]);
        float cn = fv * cA[q] + iv * gv;
        float hn = ov * fmaxf(cn, 0.f);
        bool m = (flA >> (lkg * 4 + q)) & 1u;
        cA[q] = m ? cn : cA[q];
        unsigned short hh = m ? f2bf(hn) : hgA[q];
        hgA[q] = hh; hv[q] = hh;
      }
      __syncthreads();                       // prior hstA reads done
#pragma unroll
      for (int q = 0; q < 4; ++q) hstA[kt_own][lbase + q][jst] = hv[q];
      __syncthreads();
      STORE_OWN(hstA, hxE, gA, (aA & 1), aA + 1);
    }

    if (flB) {                               // ---- B compute + store ----
      if (!xvB) {
        const float* xp = xbB + (size_t)t * 128;
#pragma unroll
        for (int kt = 0; kt < 4; ++kt) {
          xaB[kt][0] = *(const float4*)(xp + kt * 32);
          xaB[kt][1] = *(const float4*)(xp + kt * 32 + 4);
        }
      }
      f32x4 acc[4];
#pragma unroll
      for (int G = 0; G < 4; ++G) acc[G] = (f32x4){bfr[G], bfr[G], bfr[G], bfr[G]};
      FragU xf[4];
#pragma unroll
      for (int kt = 0; kt < 4; ++kt) {
        xf[kt].us[0] = f2bf(xaB[kt][0].x); xf[kt].us[1] = f2bf(xaB[kt][0].y);
        xf[kt].us[2] = f2bf(xaB[kt][0].z); xf[kt].us[3] = f2bf(xaB[kt][0].w);
        xf[kt].us[4] = f2bf(xaB[kt][1].x); xf[kt].us[5] = f2bf(xaB[kt][1].y);
        xf[kt].us[6] = f2bf(xaB[kt][1].z); xf[kt].us[7] = f2bf(xaB[kt][1].w);
      }
#pragma unroll
      for (int kt = 0; kt < 4; ++kt)
#pragma unroll
        for (int G = 0; G < 4; ++G) acc[G] = mfma16(xf[kt].v, wpin[G][kt], acc[G]);
#pragma unroll
      for (int kt = 0; kt < 8; ++kt)
#pragma unroll
        for (int G = 0; G < 4; ++G) acc[G] = mfma16(hfB[kt], upin[kt][G], acc[G]);

      unsigned short hv[4];
#pragma unroll
      for (int q = 0; q < 4; ++q) {
        float iv = sigf(acc[0][q]);
        float fv = sigf(acc[1][q]);
        float gv = fmaxf(acc[2][q], 0.f);
        float ov = sigf(acc[3][q]);
        float cn = fv * cB[q] + iv * gv;
        float hn = ov * fmaxf(cn, 0.f);
        bool m = (flB >> (lkg * 4 + q)) & 1u;
        cB[q] = m ? cn : cB[q];
        unsigned short hh = m ? f2bf(hn) : hgB[q];
        hgB[q] = hh; hv[q] = hh;
      }
      __syncthreads();
#pragma unroll
      for (int q = 0; q < 4; ++q) hstB[kt_own][lbase + q][jst] = hv[q];
      __syncthreads();
      STORE_OWN(hstB, hxE, gB, (aB & 1), aB + 1);
    }

    if (flA) {                               // ---- A window: prefetch+poll --
      if (t < 1023) {
        const float* xq = xbA + (size_t)(t + 1) * 128;
#pragma unroll
        for (int kt = 0; kt < 4; ++kt) {
          xaA[kt][0] = *(const float4*)(xq + kt * 32);
          xaA[kt][1] = *(const float4*)(xq + kt * 32 + 4);
        }
        xvA = true;
      } else xvA = false;
      POLL_REMOTE(hstA, hxE, gA, (aA & 1), aA + 1);
      __syncthreads();
#pragma unroll
      for (int kt = 0; kt < 8; ++kt)
        hfA[kt] = *(const bf16x8*)&hstA[kt][lane][0];
      ++aA;
    } else xvA = false;

    if (flB) {                               // ---- B window ----
      if (t < 1023) {
        const float* xq = xbB + (size_t)(t + 1) * 128;
#pragma unroll
        for (int kt = 0; kt < 4; ++kt) {
          xaB[kt][0] = *(const float4*)(xq + kt * 32);
          xaB[kt][1] = *(const float4*)(xq + kt * 32 + 4);
        }
        xvB = true;
      } else xvB = false;
      POLL_REMOTE(hstB, hxE, gB, (aB & 1), aB + 1);
      __syncthreads();
#pragma unroll
      for (int kt = 0; kt < 8; ++kt)
        hfB[kt] = *(const bf16x8*)&hstB[kt][lane][0];
      ++aB;
    } else xvB = false;
  }

  if (w < 2) {
    int kt = 2 * s + w;
    H8 h1; h1.v = hfA[kt];
    *(uint4v*)&hfin[((size_t)gA * 8 + kt) * 512 + lane * 8] = h1.q;
    H8 h2; h2.v = hfB[kt];
    *(uint4v*)&hfin[((size_t)gB * 8 + kt) * 512 + lane * 8] = h2.q;
  }
}

// =========================== decoder ======================================
__global__ __launch_bounds__(256) __attribute__((amdgpu_waves_per_eu(1, 1)))
void dec_rnn(const float* __restrict__ x,
             const unsigned short* __restrict__ Wd0f,
             const unsigned short* __restrict__ WdLf,
             const unsigned short* __restrict__ Udf,
             const float* __restrict__ bdec,
             const unsigned short* __restrict__ Wof,
             const float* __restrict__ bout,
             const unsigned short* __restrict__ hfin,
             ull* __restrict__ hxD,
             float* __restrict__ out) {
  __shared__ __align__(16) unsigned short hstA[8][64][8];
  __shared__ __align__(16) unsigned short hstB[8][64][8];

  const int tid = threadIdx.x;
  const int w = tid >> 6, lane = tid & 63;
  const int l15 = lane & 15, lkg = lane >> 4;
  const int bid = blockIdx.x;
  const int s = bid >> 3, p = bid & 7;
  const int gA = 2 * p, gB = 2 * p + 1;
  const int b0A = gA * 16, b0B = gB * 16;
  int ntf[4];
#pragma unroll
  for (int G = 0; G < 4; ++G) ntf[G] = G * 16 + s * 4 + w;

  const bf16x8* W0l = (const bf16x8*)Wd0f + lane;
  const bf16x8* WLl = (const bf16x8*)WdLf + lane;
  const bf16x8* Ul  = (const bf16x8*)Udf + lane;

  bf16x8 upin[8][4];                          // shared by A and B
#pragma unroll
  for (int kt = 0; kt < 8; ++kt)
#pragma unroll
    for (int G = 0; G < 4; ++G) upin[kt][G] = Ul[(kt * 64 + ntf[G]) * 64];

  bf16x8 w0pin[4][2];
#pragma unroll
  for (int G = 0; G < 4; ++G)
#pragma unroll
    for (int kt = 0; kt < 2; ++kt) w0pin[G][kt] = W0l[(kt * 64 + ntf[G]) * 64];

  f32x4 latA[4], latB[4];
  {
    bf16x8 ha[8], hb[8];
#pragma unroll
    for (int kt = 0; kt < 8; ++kt) {
      ha[kt] = *(const bf16x8*)&hfin[((size_t)gA * 8 + kt) * 512 + lane * 8];
      hb[kt] = *(const bf16x8*)&hfin[((size_t)gB * 8 + kt) * 512 + lane * 8];
    }
#pragma unroll
    for (int G = 0; G < 4; ++G) {
      float bd = bdec[ntf[G] * 16 + l15];
      latA[G] = (f32x4){bd, bd, bd, bd};
      latB[G] = (f32x4){bd, bd, bd, bd};
    }
#pragma unroll
    for (int kt = 0; kt < 8; ++kt)
#pragma unroll
      for (int G = 0; G < 4; ++G) {
        bf16x8 wl = WLl[(kt * 64 + ntf[G]) * 64];
        latA[G] = mfma16(ha[kt], wl, latA[G]);
        latB[G] = mfma16(hb[kt], wl, latB[G]);
      }
  }

  bf16x8 wofr[8];                             // W_out slice (wave 0), shared
  if (w == 0) {
#pragma unroll
    for (int kt = 0; kt < 8; ++kt)
      wofr[kt] = ((const bf16x8*)Wof)[(kt * 4 + s) * 64 + lane];
  }
  const float bo = bout[s * 16 + l15];

  float cA[4], cB[4];
  bf16x8 hfA[8], hfB[8];
#pragma unroll
  for (int q = 0; q < 4; ++q) { cA[q] = 0.f; cB[q] = 0.f; }
  H8 z_; z_.u[0] = 0; z_.u[1] = 0;
#pragma unroll
  for (int kt = 0; kt < 8; ++kt) { hfA[kt] = z_.v; hfB[kt] = z_.v; }

  const float* xbA = x + (size_t)(b0A + l15) * 1024 * 128 + lkg * 8;
  const float* xbB = x + (size_t)(b0B + l15) * 1024 * 128 + lkg * 8;
  const int kt_own = 2 * s + (w >> 1);
  const int lbase = (w & 1) * 32 + (l15 >> 3) * 16 + lkg * 4;
  const int jst = l15 & 7;

  float4 xaA[2][2], xaB[2][2];
  xaA[0][0] = *(const float4*)(xbA);      xaA[0][1] = *(const float4*)(xbA + 4);
  xaA[1][0] = *(const float4*)(xbA + 32); xaA[1][1] = *(const float4*)(xbA + 36);
  xaB[0][0] = *(const float4*)(xbB);      xaB[0][1] = *(const float4*)(xbB + 4);
  xaB[1][0] = *(const float4*)(xbB + 32); xaB[1][1] = *(const float4*)(xbB + 36);

  __syncthreads();

  for (int t = 0; t < 1024; ++t) {
    {                                         // ---- A compute + store ----
      f32x4 acc[4];
#pragma unroll
      for (int G = 0; G < 4; ++G) acc[G] = latA[G];
      FragU xf[2];
#pragma unroll
      for (int kt = 0; kt < 2; ++kt) {
        xf[kt].us[0] = f2bf(xaA[kt][0].x); xf[kt].us[1] = f2bf(xaA[kt][0].y);
        xf[kt].us[2] = f2bf(xaA[kt][0].z); xf[kt].us[3] = f2bf(xaA[kt][0].w);
        xf[kt].us[4] = f2bf(xaA[kt][1].x); xf[kt].us[5] = f2bf(xaA[kt][1].y);
        xf[kt].us[6] = f2bf(xaA[kt][1].z); xf[kt].us[7] = f2bf(xaA[kt][1].w);
      }
#pragma unroll
      for (int kt = 0; kt < 2; ++kt)
#pragma unroll
        for (int G = 0; G < 4; ++G) acc[G] = mfma16(xf[kt].v, w0pin[G][kt], acc[G]);
#pragma unroll
      for (int kt = 0; kt < 8; ++kt)
#pragma unroll
        for (int G = 0; G < 4; ++G) acc[G] = mfma16(hfA[kt], upin[kt][G], acc[G]);

      unsigned short hv[4];
#pragma unroll
      for (int q = 0; q < 4; ++q) {
        float iv = sigf(acc[0][q]);
        float fv = sigf(acc[1][q]);
        float gv = fmaxf(acc[2][q], 0.f);
        float ov = sigf(acc[3][q]);
        float cn = fv * cA[q] + iv * gv;
        cA[q] = cn;
        hv[q] = f2bf(ov * fmaxf(cn, 0.f));
      }
      __syncthreads();
#pragma unroll
      for (int q = 0; q < 4; ++q) hstA[kt_own][lbase + q][jst] = hv[q];
      __syncthreads();
      STORE_OWN(hstA, hxD, gA, (t & 1), t + 1);
    }

    {                                         // ---- B compute + store ----
      f32x4 acc[4];
#pragma unroll
      for (int G = 0; G < 4; ++G) acc[G] = latB[G];
      FragU xf[2];
#pragma unroll
      for (int kt = 0; kt < 2; ++kt) {
        xf[kt].us[0] = f2bf(xaB[kt][0].x); xf[kt].us[1] = f2bf(xaB[kt][0].y);
        xf[kt].us[2] = f2bf(xaB[kt][0].z); xf[kt].us[3] = f2bf(xaB[kt][0].w);
        xf[kt].us[4] = f2bf(xaB[kt][1].x); xf[kt].us[5] = f2bf(xaB[kt][1].y);
        xf[kt].us[6] = f2bf(xaB[kt][1].z); xf[kt].us[7] = f2bf(xaB[kt][1].w);
      }
#pragma unroll
      for (int kt = 0; kt < 2; ++kt)
#pragma unroll
        for (int G = 0; G < 4; ++G) acc[G] = mfma16(xf[kt].v, w0pin[G][kt], acc[G]);
#pragma unroll
      for (int kt = 0; kt < 8; ++kt)
#pragma unroll
        for (int G = 0; G < 4; ++G) acc[G] = mfma16(hfB[kt], upin[kt][G], acc[G]);

      unsigned short hv[4];
#pragma unroll
      for (int q = 0; q < 4; ++q) {
        float iv = sigf(acc[0][q]);
        float fv = sigf(acc[1][q]);
        float gv = fmaxf(acc[2][q], 0.f);
        float ov = sigf(acc[3][q]);
        float cn = fv * cB[q] + iv * gv;
        cB[q] = cn;
        hv[q] = f2bf(ov * fmaxf(cn, 0.f));
      }
      __syncthreads();
#pragma unroll
      for (int q = 0; q < 4; ++q) hstB[kt_own][lbase + q][jst] = hv[q];
      __syncthreads();
      STORE_OWN(hstB, hxD, gB, (t & 1), t + 1);
    }

    // ---- A window: out-projA(t-1) on wave 0, poll on waves 1-3 ----
    if (t > 0 && w == 0) {
      f32x4 oa = {bo, bo, bo, bo};
#pragma unroll
      for (int kt = 0; kt < 8; ++kt) oa = mfma16(hfA[kt], wofr[kt], oa);
#pragma unroll
      for (int q = 0; q < 4; ++q)
        out[((size_t)(b0A + lkg * 4 + q) * 1024 + (t - 1)) * 64 + s * 16 + l15] = oa[q];
    }
    if (t < 1023) {
      const float* xq = xbA + (size_t)(t + 1) * 128;
      xaA[0][0] = *(const float4*)(xq);      xaA[0][1] = *(const float4*)(xq + 4);
      xaA[1][0] = *(const float4*)(xq + 32); xaA[1][1] = *(const float4*)(xq + 36);
    }
    POLL_REMOTE(hstA, hxD, gA, (t & 1), t + 1);
    __syncthreads();
#pragma unroll
    for (int kt = 0; kt < 8; ++kt)
      hfA[kt] = *(const bf16x8*)&hstA[kt][lane][0];

    // ---- B window ----
    if (t > 0 && w == 0) {
      f32x4 oa = {bo, bo, bo, bo};
#pragma unroll
      for (int kt = 0; kt < 8; ++kt) oa = mfma16(hfB[kt], wofr[kt], oa);
#pragma unroll
      for (int q = 0; q < 4; ++q)
        out[((size_t)(b0B + lkg * 4 + q) * 1024 + (t - 1)) * 64 + s * 16 + l15] = oa[q];
    }
    if (t < 1023) {
      const float* xq = xbB + (size_t)(t + 1) * 128;
      xaB[0][0] = *(const float4*)(xq);      xaB[0][1] = *(const float4*)(xq + 4);
      xaB[1][0] = *(const float4*)(xq + 32); xaB[1][1] = *(const float4*)(xq + 36);
    }
    POLL_REMOTE(hstB, hxD, gB, (t & 1), t + 1);
    __syncthreads();
#pragma unroll
    for (int kt = 0; kt < 8; ++kt)
      hfB[kt] = *(const bf16x8*)&hstB[kt][lane][0];
  }

  if (w == 0) {                               // final out-proj (t=1023)
    f32x4 oa = {bo, bo, bo, bo};
#pragma unroll
    for (int kt = 0; kt < 8; ++kt) oa = mfma16(hfA[kt], wofr[kt], oa);
#pragma unroll
    for (int q = 0; q < 4; ++q)
      out[((size_t)(b0A + lkg * 4 + q) * 1024 + 1023) * 64 + s * 16 + l15] = oa[q];
    f32x4 ob = {bo, bo, bo, bo};
#pragma unroll
    for (int kt = 0; kt < 8; ++kt) ob = mfma16(hfB[kt], wofr[kt], ob);
#pragma unroll
    for (int q = 0; q < 4; ++q)
      out[((size_t)(b0B + lkg * 4 + q) * 1024 + 1023) * 64 + s * 16 + l15] = ob[q];
  }
}

extern "C" void kernel_launch(void* const* d_in, const int* in_sizes, int n_in,
                              void* d_out, int out_size, void* d_ws, size_t ws_size,
                              hipStream_t stream) {
  const float* inputs = (const float*)d_in[0];
  const float* W_enc  = (const float*)d_in[1];
  const float* U_enc  = (const float*)d_in[2];
  const float* b_enc  = (const float*)d_in[3];
  const float* W_dec  = (const float*)d_in[4];
  const float* U_dec  = (const float*)d_in[5];
  const float* b_dec  = (const float*)d_in[6];
  const float* W_out  = (const float*)d_in[7];
  const float* b_out  = (const float*)d_in[8];

  char* ws = (char*)d_ws;
  unsigned short* Uef   = (unsigned short*)(ws + 0);        // 512K
  unsigned short* Udf   = (unsigned short*)(ws + 524288);   // 512K
  unsigned short* Wef   = (unsigned short*)(ws + 1048576);  // 256K
  unsigned short* Wd0f  = (unsigned short*)(ws + 1310720);  // 128K
  unsigned short* WdLf  = (unsigned short*)(ws + 1441792);  // 512K
  unsigned short* Wof   = (unsigned short*)(ws + 1966080);  // 32K
  unsigned short* hfin  = (unsigned short*)(ws + 1998848);  // 128K
  unsigned int*   fmask = (unsigned int*)(ws + 2129920);    // 64K
  ull*            hxE   = (ull*)(ws + 2195456);             // 384K tagged
  ull*            hxD   = (ull*)(ws + 2588672);             // 384K tagged

  mask_flags<<<1024, 256, 0, stream>>>(inputs, fmask);
  pack_frags<<<128, 256, 0, stream>>>(U_enc, Uef, 256, 1024);
  pack_frags<<<128, 256, 0, stream>>>(U_dec, Udf, 256, 1024);
  pack_frags<<<128, 256, 0, stream>>>(W_enc, Wef, 128, 1024);
  pack_frags<<<128, 256, 0, stream>>>(W_dec, Wd0f, 64, 1024);
  pack_frags<<<128, 256, 0, stream>>>(W_dec + 64 * 1024, WdLf, 256, 1024);
  pack_frags<<<32, 256, 0, stream>>>(W_out, Wof, 256, 64);

  enc_rnn<<<32, 256, 0, stream>>>(inputs, Wef, Uef, b_enc, fmask, hxE, hfin);
  dec_rnn<<<32, 256, 0, stream>>>(inputs, Wd0f, WdLf, Udf, b_dec, Wof, b_out,
                                  hfin, hxD, (float*)d_out);
}

// Round 11
// 5291.145 us; speedup vs baseline: 1.7184x; 1.7184x over previous
//
#include <hip/hip_runtime.h>

// RNN-VAE on MI355X. R11 = R8 (proven 4.96ms) + LDS-only in-loop barriers.
// 64 WGs = 16 groups x 4 N-split; U-slice fully reg-pinned; exchange via
// self-validating tagged 8B words (agent scope, MALL); waves 1-3 poll 2
// kt-slices each; wave 0 runs dec out-proj(t-1) in the poll window.
// KEY CHANGE: per-step barriers are `s_waitcnt lgkmcnt(0); s_barrier`
// (LDS ordering only) -- __syncthreads' implicit vmcnt(0) was draining
// fire-and-forget MALL store ACKs + HBM out-proj stores + x prefetch
// 3x per step (~2-3k cy of pointless stall). Tag protocol needs no vmem
// ordering; x loads and poll loads wait at their uses automatically.

typedef __bf16 bf16x8 __attribute__((ext_vector_type(8)));
typedef float f32x4 __attribute__((ext_vector_type(4)));
typedef unsigned int uint4v __attribute__((ext_vector_type(4)));
typedef unsigned long long ull;

#define DI __device__ __forceinline__

DI unsigned short f2bf(float f) {            // fp32 -> bf16 RNE
  unsigned int u = __float_as_uint(f);
  u += 0x7fffu + ((u >> 16) & 1u);
  return (unsigned short)(u >> 16);
}
DI float sigf(float v) { return 1.0f / (1.0f + __expf(-v)); }

DI void barrier_lds() {                      // LDS-only workgroup barrier
  asm volatile("s_waitcnt lgkmcnt(0)\n\ts_barrier" ::: "memory");
}

union FragU { bf16x8 v; unsigned short us[8]; };
union H8 { bf16x8 v; ull u[2]; uint4v q; };

DI f32x4 mfma16(bf16x8 a, bf16x8 b, f32x4 c) {
  return __builtin_amdgcn_mfma_f32_16x16x32_bf16(a, b, c, 0, 0, 0);
}
DI ull ald(const ull* p) {
  return __hip_atomic_load(p, __ATOMIC_RELAXED, __HIP_MEMORY_SCOPE_AGENT);
}

// ---- weight fragment packing (unchanged) ----
__global__ void pack_frags(const float* __restrict__ src,
                           unsigned short* __restrict__ dst, int K, int N) {
  int KT = K >> 5, NT = N >> 4;
  int total = KT * NT * 64;
  for (int idx = blockIdx.x * blockDim.x + threadIdx.x; idx < total;
       idx += gridDim.x * blockDim.x) {
    int lane = idx & 63;
    int fi = idx >> 6;
    int nt = fi % NT;
    int kt = fi / NT;
    int r0 = kt * 32 + (lane >> 4) * 8;
    int col = nt * 16 + (lane & 15);
    unsigned int w[4];
#pragma unroll
    for (int p = 0; p < 4; ++p) {
      unsigned int lo = f2bf(src[(size_t)(r0 + 2 * p) * N + col]);
      unsigned int hi = f2bf(src[(size_t)(r0 + 2 * p + 1) * N + col]);
      w[p] = lo | (hi << 16);
    }
    *(uint4v*)(dst + (size_t)idx * 8) = (uint4v){w[0], w[1], w[2], w[3]};
  }
}

// ---- per-(b,t) nonzero mask (unchanged) ----
__global__ void mask_flags(const float* __restrict__ x,
                           unsigned int* __restrict__ fmask) {
  const int t = blockIdx.x;
  const int b = threadIdx.x;
  const float* p = x + ((size_t)b * 1024 + t) * 128;
  bool nz = false;
#pragma unroll 8
  for (int k = 0; k < 32; ++k) {
    float4 v = *(const float4*)(p + k * 4);
    nz = nz || v.x != 0.f || v.y != 0.f || v.z != 0.f || v.w != 0.f;
  }
  unsigned long long bal = __ballot((int)nz);
  if ((threadIdx.x & 15) == 0)
    fmask[(size_t)(b >> 4) * 1024 + t] =
        (unsigned int)((bal >> (threadIdx.x & 48)) & 0xFFFFull);
}

// store own 2 kt-slices as tagged 3-ull words (tid<128), fire-and-forget
#define STORE_OWN(HX, PAR, TAG) do {                                        \
    if (tid < 128) {                                                        \
      const int kth = tid >> 6, word = tid & 63;                            \
      H8 hh; hh.q = *(const uint4v*)&hstage[2 * s + kth][word][0];          \
      const ull tg = (ull)(TAG);                                            \
      ull Aw = (hh.u[0] & 0xFFFFFFFFFFFFULL) | (tg << 48);                  \
      ull Bw = ((hh.u[0] >> 48) | ((hh.u[1] & 0xFFFFFFFFULL) << 16)) |      \
               (tg << 48);                                                  \
      ull Cw = (hh.u[1] >> 32) | (tg << 48);                                \
      ull* p_ = (HX) + (size_t)(g * 2 + (PAR)) * 1536 +                     \
                ((2 * s + kth) * 64 + word) * 3;                            \
      __hip_atomic_store(p_ + 0, Aw, __ATOMIC_RELAXED, __HIP_MEMORY_SCOPE_AGENT); \
      __hip_atomic_store(p_ + 1, Bw, __ATOMIC_RELAXED, __HIP_MEMORY_SCOPE_AGENT); \
      __hip_atomic_store(p_ + 2, Cw, __ATOMIC_RELAXED, __HIP_MEMORY_SCOPE_AGENT); \
    } } while (0)

// waves 1..3: poll partner WG's 2 kt-slices until tags==TAG, write hstage
#define POLL_REMOTE(HX, PAR, TAG) do {                                      \
    if (w >= 1) {                                                           \
      const int s2_ = (w - 1) + ((w - 1) >= s ? 1 : 0);                     \
      const int rk0 = 2 * s2_, rk1 = rk0 + 1;                               \
      const ull* hb_ = (HX) + (size_t)(g * 2 + (PAR)) * 1536;               \
      const ull* q0 = hb_ + (rk0 * 64 + lane) * 3;                          \
      const ull* q1 = hb_ + (rk1 * 64 + lane) * 3;                          \
      const ull tg = (ull)(TAG);                                            \
      ull A0, A1, A2, B0, B1, B2;                                           \
      unsigned it_ = 0;                                                     \
      for (;;) {                                                            \
        A0 = ald(q0); A1 = ald(q0 + 1); A2 = ald(q0 + 2);                   \
        B0 = ald(q1); B1 = ald(q1 + 1); B2 = ald(q1 + 2);                   \
        bool ok_ = ((A0 >> 48) == tg) && ((A1 >> 48) == tg) &&              \
                   ((A2 >> 48) == tg) && ((B0 >> 48) == tg) &&              \
                   ((B1 >> 48) == tg) && ((B2 >> 48) == tg);                \
        if (ok_ || ++it_ > (1u << 14)) break;                               \
      }                                                                     \
      H8 h0_, h1_;                                                          \
      h0_.u[0] = (A0 & 0xFFFFFFFFFFFFULL) | (A1 << 48);                     \
      h0_.u[1] = ((A1 >> 16) & 0xFFFFFFFFULL) | ((A2 & 0xFFFFFFFFULL) << 32); \
      h1_.u[0] = (B0 & 0xFFFFFFFFFFFFULL) | (B1 << 48);                     \
      h1_.u[1] = ((B1 >> 16) & 0xFFFFFFFFULL) | ((B2 & 0xFFFFFFFFULL) << 32); \
      *(uint4v*)&hstage[rk0][lane][0] = h0_.q;                              \
      *(uint4v*)&hstage[rk1][lane][0] = h1_.q;                              \
    } } while (0)

// =========================== encoder ======================================
__global__ __launch_bounds__(256) __attribute__((amdgpu_waves_per_eu(1, 1)))
void enc_rnn(const float* __restrict__ x,
             const unsigned short* __restrict__ Wef,
             const unsigned short* __restrict__ Uef,
             const float* __restrict__ benc,
             const unsigned int* __restrict__ fmask,
             ull* __restrict__ hxE,                    // [16][2][512][3] ull
             unsigned short* __restrict__ hfin) {
  __shared__ __align__(16) unsigned short hstage[8][64][8];   // 8KB

  const int tid = threadIdx.x;
  const int w = tid >> 6, lane = tid & 63;
  const int l15 = lane & 15, lkg = lane >> 4;
  const int bid = blockIdx.x;
  const int s = bid >> 4, g = bid & 15;
  const int b0 = g * 16;
  int ntf[4];
#pragma unroll
  for (int G = 0; G < 4; ++G) ntf[G] = G * 16 + s * 4 + w;

  const bf16x8* Wl = (const bf16x8*)Wef + lane;
  const bf16x8* Ul = (const bf16x8*)Uef + lane;
  const unsigned int* flagp = fmask + (size_t)g * 1024;

  bf16x8 upin[8][4];                         // full U slice in registers
#pragma unroll
  for (int kt = 0; kt < 8; ++kt)
#pragma unroll
    for (int G = 0; G < 4; ++G) upin[kt][G] = Ul[(kt * 64 + ntf[G]) * 64];

  bf16x8 wpin[4][4];                         // W kt0..3
#pragma unroll
  for (int G = 0; G < 4; ++G)
#pragma unroll
    for (int kt = 0; kt < 4; ++kt) wpin[G][kt] = Wl[(kt * 64 + ntf[G]) * 64];

  float bfr[4];
#pragma unroll
  for (int G = 0; G < 4; ++G) bfr[G] = benc[ntf[G] * 16 + l15];

  float c4[4];
  unsigned short hreg[4];
  bf16x8 hfr[8];
#pragma unroll
  for (int q = 0; q < 4; ++q) { c4[q] = 0.f; hreg[q] = 0; }
  H8 z_; z_.u[0] = 0; z_.u[1] = 0;
#pragma unroll
  for (int kt = 0; kt < 8; ++kt) hfr[kt] = z_.v;

  const float* xbase = x + (size_t)(b0 + l15) * 1024 * 128 + lkg * 8;
  const int kt_own = 2 * s + (w >> 1);
  const int lbase = (w & 1) * 32 + (l15 >> 3) * 16 + lkg * 4;
  const int jst = l15 & 7;
  int a = 0;
  bool xvalid = false;
  float4 xa[4][2];

  __syncthreads();

  for (int t = 0; t < 1024; ++t) {
    const unsigned int flag_t = flagp[t];
    if (flag_t == 0u) { xvalid = false; continue; }   // group-uniform skip

    if (!xvalid) {
      const float* xp = xbase + (size_t)t * 128;
#pragma unroll
      for (int kt = 0; kt < 4; ++kt) {
        xa[kt][0] = *(const float4*)(xp + kt * 32);
        xa[kt][1] = *(const float4*)(xp + kt * 32 + 4);
      }
    }

    f32x4 acc[4];
#pragma unroll
    for (int G = 0; G < 4; ++G) acc[G] = (f32x4){bfr[G], bfr[G], bfr[G], bfr[G]};

    FragU xf[4];
#pragma unroll
    for (int kt = 0; kt < 4; ++kt) {
      xf[kt].us[0] = f2bf(xa[kt][0].x); xf[kt].us[1] = f2bf(xa[kt][0].y);
      xf[kt].us[2] = f2bf(xa[kt][0].z); xf[kt].us[3] = f2bf(xa[kt][0].w);
      xf[kt].us[4] = f2bf(xa[kt][1].x); xf[kt].us[5] = f2bf(xa[kt][1].y);
      xf[kt].us[6] = f2bf(xa[kt][1].z); xf[kt].us[7] = f2bf(xa[kt][1].w);
    }
#pragma unroll
    for (int kt = 0; kt < 4; ++kt)
#pragma unroll
      for (int G = 0; G < 4; ++G) acc[G] = mfma16(xf[kt].v, wpin[G][kt], acc[G]);

#pragma unroll
    for (int kt = 0; kt < 8; ++kt)
#pragma unroll
      for (int G = 0; G < 4; ++G) acc[G] = mfma16(hfr[kt], upin[kt][G], acc[G]);

    unsigned short hv[4];
#pragma unroll
    for (int q = 0; q < 4; ++q) {
      float iv = sigf(acc[0][q]);
      float fv = sigf(acc[1][q]);
      float gv = fmaxf(acc[2][q], 0.f);
      float ov = sigf(acc[3][q]);
      float cn = fv * c4[q] + iv * gv;
      float hn = ov * fmaxf(cn, 0.f);
      bool m = (flag_t >> (lkg * 4 + q)) & 1u;
      c4[q] = m ? cn : c4[q];
      unsigned short hh = m ? f2bf(hn) : hreg[q];
      hreg[q] = hh;
      hv[q] = hh;
    }

    barrier_lds();                            // b1: prior hstage reads done
#pragma unroll
    for (int q = 0; q < 4; ++q) hstage[kt_own][lbase + q][jst] = hv[q];
    barrier_lds();                            // b2: transpose visible

    STORE_OWN(hxE, (a & 1), a + 1);

    if (t < 1023) {                           // poll-window: prefetch x[t+1]
      const float* xq = xbase + (size_t)(t + 1) * 128;
#pragma unroll
      for (int kt = 0; kt < 4; ++kt) {
        xa[kt][0] = *(const float4*)(xq + kt * 32);
        xa[kt][1] = *(const float4*)(xq + kt * 32 + 4);
      }
      xvalid = true;
    } else xvalid = false;

    POLL_REMOTE(hxE, (a & 1), a + 1);
    barrier_lds();                            // b3: hstage fully populated

#pragma unroll
    for (int kt = 0; kt < 8; ++kt)
      hfr[kt] = *(const bf16x8*)&hstage[kt][lane][0];
    ++a;
  }

  if (w < 2) {
    int kt = 2 * s + w;
    H8 hh_; hh_.v = hfr[kt];
    *(uint4v*)&hfin[((size_t)g * 8 + kt) * 512 + lane * 8] = hh_.q;
  }
}

// =========================== decoder ======================================
__global__ __launch_bounds__(256) __attribute__((amdgpu_waves_per_eu(1, 1)))
void dec_rnn(const float* __restrict__ x,
             const unsigned short* __restrict__ Wd0f,
             const unsigned short* __restrict__ WdLf,
             const unsigned short* __restrict__ Udf,
             const float* __restrict__ bdec,
             const unsigned short* __restrict__ Wof,
             const float* __restrict__ bout,
             const unsigned short* __restrict__ hfin,
             ull* __restrict__ hxD,
             float* __restrict__ out) {
  __shared__ __align__(16) unsigned short hstage[8][64][8];   // 8KB

  const int tid = threadIdx.x;
  const int w = tid >> 6, lane = tid & 63;
  const int l15 = lane & 15, lkg = lane >> 4;
  const int bid = blockIdx.x;
  const int s = bid >> 4, g = bid & 15;
  const int b0 = g * 16;
  int ntf[4];
#pragma unroll
  for (int G = 0; G < 4; ++G) ntf[G] = G * 16 + s * 4 + w;

  const bf16x8* W0l = (const bf16x8*)Wd0f + lane;
  const bf16x8* WLl = (const bf16x8*)WdLf + lane;
  const bf16x8* Ul  = (const bf16x8*)Udf + lane;

  bf16x8 upin[8][4];
#pragma unroll
  for (int kt = 0; kt < 8; ++kt)
#pragma unroll
    for (int G = 0; G < 4; ++G) upin[kt][G] = Ul[(kt * 64 + ntf[G]) * 64];

  bf16x8 w0pin[4][2];
#pragma unroll
  for (int G = 0; G < 4; ++G)
#pragma unroll
    for (int kt = 0; kt < 2; ++kt) w0pin[G][kt] = W0l[(kt * 64 + ntf[G]) * 64];

  f32x4 lat[4];
  {
    bf16x8 ha[8];
#pragma unroll
    for (int kt = 0; kt < 8; ++kt)
      ha[kt] = *(const bf16x8*)&hfin[((size_t)g * 8 + kt) * 512 + lane * 8];
#pragma unroll
    for (int G = 0; G < 4; ++G) {
      float bd = bdec[ntf[G] * 16 + l15];
      lat[G] = (f32x4){bd, bd, bd, bd};
    }
#pragma unroll
    for (int kt = 0; kt < 8; ++kt)
#pragma unroll
      for (int G = 0; G < 4; ++G)
        lat[G] = mfma16(ha[kt], WLl[(kt * 64 + ntf[G]) * 64], lat[G]);
  }

  bf16x8 wofr[8];
  if (w == 0) {
#pragma unroll
    for (int kt = 0; kt < 8; ++kt)
      wofr[kt] = ((const bf16x8*)Wof)[(kt * 4 + s) * 64 + lane];
  }
  const float bo = bout[s * 16 + l15];

  float c4[4];
  bf16x8 hfr[8];
#pragma unroll
  for (int q = 0; q < 4; ++q) c4[q] = 0.f;
  H8 z_; z_.u[0] = 0; z_.u[1] = 0;
#pragma unroll
  for (int kt = 0; kt < 8; ++kt) hfr[kt] = z_.v;

  const float* xbase = x + (size_t)(b0 + l15) * 1024 * 128 + lkg * 8;
  const int kt_own = 2 * s + (w >> 1);
  const int lbase = (w & 1) * 32 + (l15 >> 3) * 16 + lkg * 4;
  const int jst = l15 & 7;

  float4 xa[2][2];
  xa[0][0] = *(const float4*)(xbase);      xa[0][1] = *(const float4*)(xbase + 4);
  xa[1][0] = *(const float4*)(xbase + 32); xa[1][1] = *(const float4*)(xbase + 36);

  __syncthreads();

  for (int t = 0; t < 1024; ++t) {
    f32x4 acc[4];
#pragma unroll
    for (int G = 0; G < 4; ++G) acc[G] = lat[G];

    FragU xf[2];
#pragma unroll
    for (int kt = 0; kt < 2; ++kt) {
      xf[kt].us[0] = f2bf(xa[kt][0].x); xf[kt].us[1] = f2bf(xa[kt][0].y);
      xf[kt].us[2] = f2bf(xa[kt][0].z); xf[kt].us[3] = f2bf(xa[kt][0].w);
      xf[kt].us[4] = f2bf(xa[kt][1].x); xf[kt].us[5] = f2bf(xa[kt][1].y);
      xf[kt].us[6] = f2bf(xa[kt][1].z); xf[kt].us[7] = f2bf(xa[kt][1].w);
    }
#pragma unroll
    for (int kt = 0; kt < 2; ++kt)
#pragma unroll
      for (int G = 0; G < 4; ++G) acc[G] = mfma16(xf[kt].v, w0pin[G][kt], acc[G]);

#pragma unroll
    for (int kt = 0; kt < 8; ++kt)
#pragma unroll
      for (int G = 0; G < 4; ++G) acc[G] = mfma16(hfr[kt], upin[kt][G], acc[G]);

    unsigned short hv[4];
#pragma unroll
    for (int q = 0; q < 4; ++q) {
      float iv = sigf(acc[0][q]);
      float fv = sigf(acc[1][q]);
      float gv = fmaxf(acc[2][q], 0.f);
      float ov = sigf(acc[3][q]);
      float cn = fv * c4[q] + iv * gv;
      float hn = ov * fmaxf(cn, 0.f);
      c4[q] = cn;
      hv[q] = f2bf(hn);
    }

    barrier_lds();                            // b1
#pragma unroll
    for (int q = 0; q < 4; ++q) hstage[kt_own][lbase + q][jst] = hv[q];
    barrier_lds();                            // b2

    STORE_OWN(hxD, (t & 1), t + 1);

    // poll-window: out-proj(t-1) on wave 0 (hfr = h_{t-1}); x prefetch
    if (t > 0 && w == 0) {
      f32x4 oa = {bo, bo, bo, bo};
#pragma unroll
      for (int kt = 0; kt < 8; ++kt) oa = mfma16(hfr[kt], wofr[kt], oa);
#pragma unroll
      for (int q = 0; q < 4; ++q)
        out[((size_t)(b0 + lkg * 4 + q) * 1024 + (t - 1)) * 64 + s * 16 + l15] = oa[q];
    }
    if (t < 1023) {
      const float* xq = xbase + (size_t)(t + 1) * 128;
      xa[0][0] = *(const float4*)(xq);      xa[0][1] = *(const float4*)(xq + 4);
      xa[1][0] = *(const float4*)(xq + 32); xa[1][1] = *(const float4*)(xq + 36);
    }

    POLL_REMOTE(hxD, (t & 1), t + 1);
    barrier_lds();                            // b3

#pragma unroll
    for (int kt = 0; kt < 8; ++kt)
      hfr[kt] = *(const bf16x8*)&hstage[kt][lane][0];
  }

  if (w == 0) {                               // final out-proj (t=1023)
    f32x4 oa = {bo, bo, bo, bo};
#pragma unroll
    for (int kt = 0; kt < 8; ++kt) oa = mfma16(hfr[kt], wofr[kt], oa);
#pragma unroll
    for (int q = 0; q < 4; ++q)
      out[((size_t)(b0 + lkg * 4 + q) * 1024 + 1023) * 64 + s * 16 + l15] = oa[q];
  }
}

extern "C" void kernel_launch(void* const* d_in, const int* in_sizes, int n_in,
                              void* d_out, int out_size, void* d_ws, size_t ws_size,
                              hipStream_t stream) {
  const float* inputs = (const float*)d_in[0];
  const float* W_enc  = (const float*)d_in[1];
  const float* U_enc  = (const float*)d_in[2];
  const float* b_enc  = (const float*)d_in[3];
  const float* W_dec  = (const float*)d_in[4];
  const float* U_dec  = (const float*)d_in[5];
  const float* b_dec  = (const float*)d_in[6];
  const float* W_out  = (const float*)d_in[7];
  const float* b_out  = (const float*)d_in[8];

  char* ws = (char*)d_ws;
  unsigned short* Uef   = (unsigned short*)(ws + 0);        // 512K
  unsigned short* Udf   = (unsigned short*)(ws + 524288);   // 512K
  unsigned short* Wef   = (unsigned short*)(ws + 1048576);  // 256K
  unsigned short* Wd0f  = (unsigned short*)(ws + 1310720);  // 128K
  unsigned short* WdLf  = (unsigned short*)(ws + 1441792);  // 512K
  unsigned short* Wof   = (unsigned short*)(ws + 1966080);  // 32K
  unsigned short* hfin  = (unsigned short*)(ws + 1998848);  // 128K
  unsigned int*   fmask = (unsigned int*)(ws + 2129920);    // 64K
  ull*            hxE   = (ull*)(ws + 2195456);             // 384K tagged
  ull*            hxD   = (ull*)(ws + 2588672);             // 384K tagged

  mask_flags<<<1024, 256, 0, stream>>>(inputs, fmask);
  pack_frags<<<128, 256, 0, stream>>>(U_enc, Uef, 256, 1024);
  pack_frags<<<128, 256, 0, stream>>>(U_dec, Udf, 256, 1024);
  pack_frags<<<128, 256, 0, stream>>>(W_enc, Wef, 128, 1024);
  pack_frags<<<128, 256, 0, stream>>>(W_dec, Wd0f, 64, 1024);
  pack_frags<<<128, 256, 0, stream>>>(W_dec + 64 * 1024, WdLf, 256, 1024);
  pack_frags<<<32, 256, 0, stream>>>(W_out, Wof, 256, 64);

  enc_rnn<<<64, 256, 0, stream>>>(inputs, Wef, Uef, b_enc, fmask, hxE, hfin);
  dec_rnn<<<64, 256, 0, stream>>>(inputs, Wd0f, WdLf, Udf, b_dec, Wof, b_out,
                                  hfin, hxD, (float*)d_out);
}